// Round 2
// baseline (105.560 us; speedup 1.0000x reference)
//
#include <hip/hip_runtime.h>

#define EPS 1e-7f
#define T_DIM 2048
#define TP1   2049
#define H_DIM 8
#define B_DIM 8

#define NFRAG 146          // fb_phys in [0,146): b0 = fbp*16 - 160 (first 8 entries all-zero pad)
#define NST   33           // 64-wide s-tiles per b (covers s in [0,2112), zero past 2048)
#define AREG  10240        // A region bytes per LDS buffer (10 x 1KB entries)
#define BUFSZ 26624        // A 10KB + B 2 x 8KB

#define J1_BLOCKS 292      // 8*146*64/256 fragA entries
#define J2_BLOCKS 264      // 8 b * 33 st transpose tiles
#define MM_BLOCKS 544      // 17 t0-levels * 4 b-groups * 8 heads
#define J3_BLOCKS 4098     // head-H rows: 8*2049/4

typedef short v8s __attribute__((ext_vector_type(8)));
typedef float v4f __attribute__((ext_vector_type(4)));

static __device__ __forceinline__ unsigned short f2bf(float f) {
  union { float f; unsigned u; } v; v.f = f;
  unsigned r = v.u + 0x7fffu + ((v.u >> 16) & 1u);  // RTNE
  return (unsigned short)(r >> 16);
}

static __device__ __forceinline__ void load_lds16(const void* g, void* l) {
  __builtin_amdgcn_global_load_lds(
      (const __attribute__((address_space(1))) unsigned int*)g,
      (__attribute__((address_space(3))) unsigned int*)l, 16, 0, 0);
}

// prep: [J1] MFMA A-fragment table (with 8 leading zero entries), [J2] x -> bf16
// transpose into swizzled 8KB chunks xT[b][st][dd][slot^(dd&7)][8].
__global__ __launch_bounds__(256) void prep(const float* __restrict__ x,
                                            const float* __restrict__ W,
                                            unsigned short* __restrict__ fragA,
                                            unsigned short* __restrict__ xT) {
  __shared__ float tile[64][65];
  int bid = blockIdx.x;
  if (bid < J1_BLOCKS) {
    // fragA[((h*NFRAG+fbp)*64+lane)*8]: A[m=lm][k=8q+j] = k_h[b0+lm-8q-j], b0=fbp*16-160
    int tid = bid * 256 + threadIdx.x;
    int blk = tid >> 6, lane = tid & 63;
    int h = blk / NFRAG, fbp = blk - h * NFRAG;
    int b0 = fbp * 16 - 160;
    int lm = lane & 15, quad = lane >> 4;
    v8s frag;
    #pragma unroll
    for (int j = 0; j < 8; ++j) {
      int d = b0 + lm - 8 * quad - j;
      float v = 0.0f;
      if (d >= 0 && d < T_DIM) v = __expf(W[d * H_DIM + h]);
      else if (d == T_DIM) v = 1.0f;
      frag[j] = (short)f2bf(v);
    }
    *(v8s*)(fragA + (size_t)tid * 8) = frag;
    return;
  }
  bid -= J1_BLOCKS;
  {
    int b = bid / NST, st = bid - b * NST;
    int s0 = st * 64;
    int tid = threadIdx.x;
    int c = tid & 63, r4 = tid >> 6;
    #pragma unroll
    for (int i = 0; i < 16; ++i) {
      int sl = r4 * 16 + i;
      int s = s0 + sl;
      tile[sl][c] = (s < T_DIM) ? x[((size_t)b * T_DIM + s) * 64 + c] : 0.0f;
    }
    __syncthreads();
    // chunk byte layout: dd*128 + p*16 + j*2 holds s_local = (p^(dd&7))*8 + j
    int dd = tid >> 2, pb = (tid & 3) * 2;
    unsigned short* dst = xT + ((size_t)(b * NST + st) << 12) + dd * 64;
    #pragma unroll
    for (int e = 0; e < 2; ++e) {
      int p = pb + e;
      int sb = ((p ^ (dd & 7)) << 3);
      v8s o;
      #pragma unroll
      for (int j = 0; j < 8; ++j) o[j] = (short)f2bf(tile[sb + j][dd]);
      *(v8s*)(dst + p * 8) = o;
    }
  }
}

// Fat blocks (bid < MM_BLOCKS): block = (h, b-pair, 128 rows), 4 waves:
//   wm = w&1 owns a 64-row half (tw = t0 + 64*wm), wb = w>>1 owns one b.
// K loop in BK=64 steps. Schedule: counted-vmcnt double buffer (T3+T4, m201
// discipline): prologue stages both buffers; each step waits vmcnt(myloads)
// (older stage landed), raw s_barrier, MFMA cluster under setprio (T5), second
// barrier, then immediately re-stage the consumed buffer for step it+2 so its
// loads fly for a whole step. Never vmcnt(0) in the main loop.
// h = bid&7 pins one head per XCD (L2 working set fragA[h]+xT ~2.3MB/XCD).
// Trailing blocks: head-H l2norm of xp (independent of prep; overlaps MM).
__global__ __launch_bounds__(256) void toeplitz_mm(const float* __restrict__ x,
                                                   const unsigned short* __restrict__ fragA,
                                                   const unsigned short* __restrict__ xT,
                                                   float* __restrict__ out) {
  __shared__ __align__(16) char smem[2][BUFSZ];

  int bid = blockIdx.x;
  if (bid >= MM_BLOCKS) {  // head H: single l2norm of xp
    int row = (bid - MM_BLOCKS) * 4 + (threadIdx.x >> 6);
    int b = row / TP1, t = row - b * TP1;
    int dd = threadIdx.x & 63;
    float v = (t < T_DIM) ? x[((size_t)b * T_DIM + t) * 64 + dd] : 0.0f;
    float ss = v * v;
    ss += __shfl_xor(ss, 1);  ss += __shfl_xor(ss, 2);
    ss += __shfl_xor(ss, 4);  ss += __shfl_xor(ss, 8);
    ss += __shfl_xor(ss, 16); ss += __shfl_xor(ss, 32);
    float inv = 1.0f / (sqrtf(ss) + EPS);
    __builtin_nontemporal_store(v * inv,
        &out[(((size_t)(H_DIM * B_DIM + b) * TP1 + t) << 6) + dd]);
    return;
  }

  const int lane = threadIdx.x & 63;
  const int w    = threadIdx.x >> 6;
  const int wm   = w & 1;
  const int wb   = w >> 1;
  const int lm   = lane & 15;
  const int quad = lane >> 4;

  const int h   = bid & 7;
  const int bg  = (bid >> 3) & 3;
  const int lvl = bid >> 5;                 // 0..16, longest tiles first
  const int t0  = T_DIM - lvl * 128;
  const int tw  = t0 + 64 * wm;
  const int b   = bg * 2 + wb;
  const bool active = (tw <= T_DIM);
  const int cap = tw + 32;                  // last valid 32-chunk base for this wave

  const int NS = (min(t0 + 96, T_DIM) >> 6) + 1;   // always >= 2

  const unsigned short* fA = fragA + (size_t)h * NFRAG * 512 + lane * 8;

  // Stage step 'it' into smem[bufi]: units 0..9 = A entries E0p..E0p+9 (1KB each),
  // units 10..25 = B pieces (2 b's x 8 x 1KB). Unit u = w + 4*i: waves 0,1 issue
  // 7 loads; waves 2,3 issue 6 (used for the counted vmcnt below).
#define STAGE(bufi, it) do {                                                   \
    int _s0 = (it) << 6;                                                       \
    int _E0p = ((t0 - _s0 + 32) >> 4) + 6;                                     \
    const unsigned short* _A = fA + (size_t)_E0p * 512;                        \
    const unsigned short* _B = xT + ((size_t)((bg * 2) * NST + (_s0 >> 6)) << 12) + lane * 8; \
    char* _lb = &smem[bufi][0];                                                \
    _Pragma("unroll")                                                          \
    for (int _i = 0; _i < 7; ++_i) {                                           \
      int _u = w + _i * 4;                                                     \
      if (_u < 26) {                                                           \
        const unsigned short* _src = (_u < 10)                                 \
            ? (_A + (size_t)_u * 512)                                          \
            : (_B + (((_u - 10) >> 3) * (NST * 4096)) + (((_u - 10) & 7) * 512)); \
        load_lds16(_src, _lb + _u * 1024);                                     \
      }                                                                        \
    }                                                                          \
  } while (0)

  v4f acc[4][4] = {};  // rows tw+16*mt+4*quad+r, cols (b, 16*nt+lm)

  STAGE(0, 0);
  STAGE(1, 1);
  int buf = 0;
  for (int it = 0; it < NS; ++it) {
    // Wait for step-it's stage (the older of the <=2 in flight), never drain.
    if (it < NS - 1) {
      if (w < 2) asm volatile("s_waitcnt vmcnt(7)" ::: "memory");
      else       asm volatile("s_waitcnt vmcnt(6)" ::: "memory");
    } else {
      asm volatile("s_waitcnt vmcnt(0)" ::: "memory");
    }
    __builtin_amdgcn_s_barrier();
    __builtin_amdgcn_sched_barrier(0);

    const char* Ab = &smem[buf][0];
    const char* Bb = Ab + AREG + wb * 8192;
    int s0 = it << 6;
    __builtin_amdgcn_s_setprio(1);
    #pragma unroll
    for (int kk = 0; kk < 2; ++kk) {
      if (active && (s0 + 32 * kk <= cap)) {
        v8s af[4], bf[4];
        #pragma unroll
        for (int mt = 0; mt < 4; ++mt)
          af[mt] = *(const v8s*)(Ab + (2 + 4 * wm - 2 * kk + mt) * 1024 + lane * 16);
        #pragma unroll
        for (int nt = 0; nt < 4; ++nt)
          bf[nt] = *(const v8s*)(Bb + nt * 2048 + lm * 128 +
                                 ((((kk << 2) | quad) ^ (lm & 7)) << 4));
        #pragma unroll
        for (int mt = 0; mt < 4; ++mt)
          #pragma unroll
          for (int nt = 0; nt < 4; ++nt)
            acc[mt][nt] = __builtin_amdgcn_mfma_f32_16x16x32_bf16(af[mt], bf[nt],
                                                                  acc[mt][nt], 0, 0, 0);
      }
    }
    __builtin_amdgcn_s_setprio(0);
    __builtin_amdgcn_sched_barrier(0);
    __builtin_amdgcn_s_barrier();   // all waves done reading smem[buf]
    if (it + 2 < NS) STAGE(buf, it + 2);
    buf ^= 1;
  }

  if (!active) return;

  // Epilogue: double l2-norm over dd (softmax Z cancels up to eps ~3e-7).
  // C/D layout: col = lane&15 (dd offset), row = quad*4 + reg.
  #pragma unroll
  for (int mt = 0; mt < 4; ++mt) {
    #pragma unroll
    for (int r = 0; r < 4; ++r) {
      float ss = 0.0f;
      #pragma unroll
      for (int nt = 0; nt < 4; ++nt) { float a = acc[mt][nt][r]; ss += a * a; }
      ss += __shfl_xor(ss, 1);
      ss += __shfl_xor(ss, 2);
      ss += __shfl_xor(ss, 4);
      ss += __shfl_xor(ss, 8);
      int t = tw + 16 * mt + 4 * quad + r;
      if (t <= T_DIM) {
        float n1 = sqrtf(ss);
        float u  = n1 / (n1 + EPS);
        float inv = 1.0f / ((n1 + EPS) * (u + EPS));
        float* op = out + (((size_t)(h * B_DIM + b) * TP1 + t) << 6) + lm;
        #pragma unroll
        for (int nt = 0; nt < 4; ++nt)
          __builtin_nontemporal_store(acc[mt][nt][r] * inv, op + 16 * nt);
      }
    }
  }
#undef STAGE
}

extern "C" void kernel_launch(void* const* d_in, const int* in_sizes, int n_in,
                              void* d_out, int out_size, void* d_ws, size_t ws_size,
                              hipStream_t stream) {
  const float* x = (const float*)d_in[0];   // [8, 2048, 64] fp32
  const float* W = (const float*)d_in[1];   // [2048, 8] fp32
  float* out = (float*)d_out;               // [9, 8, 2049, 64] fp32

  unsigned short* xT    = (unsigned short*)d_ws;                    // 8*33*8192 = 2,162,688 B
  unsigned short* fragA = (unsigned short*)((char*)d_ws + 2162688); // 8*146*1024 = 1,196,032 B

  hipLaunchKernelGGL(prep, dim3(J1_BLOCKS + J2_BLOCKS), dim3(256), 0, stream,
                     x, W, fragA, xT);
  hipLaunchKernelGGL(toeplitz_mm, dim3(MM_BLOCKS + J3_BLOCKS), dim3(256), 0, stream,
                     x, fragA, xT, out);
}

// Round 3
// 102.358 us; speedup vs baseline: 1.0313x; 1.0313x over previous
//
#include <hip/hip_runtime.h>

#define EPS 1e-7f
#define T_DIM 2048
#define TP1   2049
#define H_DIM 8
#define B_DIM 8

#define NFRAG 146          // fb_phys in [0,146): b0 = fbp*16 - 160 (first 8 entries all-zero pad)
#define NST   33           // 64-wide s-tiles per b (covers s in [0,2112), zero past 2048)
#define AREG  10240        // A region bytes per LDS buffer (10 x 1KB entries)
#define BUFSZ 26624        // A 10KB + B 2 x 8KB

#define J1_BLOCKS 292      // 8*146*64/256 fragA entries
#define J2_BLOCKS 264      // 8 b * 33 st transpose tiles
#define MM_BLOCKS 544      // 17 t0-levels * 4 b-groups * 8 heads
#define J3_BLOCKS 4098     // head-H rows: 8*2049/4

typedef short v8s __attribute__((ext_vector_type(8)));
typedef float v4f __attribute__((ext_vector_type(4)));

static __device__ __forceinline__ unsigned short f2bf(float f) {
  union { float f; unsigned u; } v; v.f = f;
  unsigned r = v.u + 0x7fffu + ((v.u >> 16) & 1u);  // RTNE
  return (unsigned short)(r >> 16);
}

static __device__ __forceinline__ void load_lds16(const void* g, void* l) {
  __builtin_amdgcn_global_load_lds(
      (const __attribute__((address_space(1))) unsigned int*)g,
      (__attribute__((address_space(3))) unsigned int*)l, 16, 0, 0);
}

// prep: [J1] MFMA A-fragment table (with 8 leading zero entries), [J2] x -> bf16
// transpose into swizzled 8KB chunks xT[b][st][dd][slot^(dd&7)][8].
__global__ __launch_bounds__(256) void prep(const float* __restrict__ x,
                                            const float* __restrict__ W,
                                            unsigned short* __restrict__ fragA,
                                            unsigned short* __restrict__ xT) {
  __shared__ float tile[64][65];
  int bid = blockIdx.x;
  if (bid < J1_BLOCKS) {
    // fragA[((h*NFRAG+fbp)*64+lane)*8]: A[m=lm][k=8q+j] = k_h[b0+lm-8q-j], b0=fbp*16-160
    int tid = bid * 256 + threadIdx.x;
    int blk = tid >> 6, lane = tid & 63;
    int h = blk / NFRAG, fbp = blk - h * NFRAG;
    int b0 = fbp * 16 - 160;
    int lm = lane & 15, quad = lane >> 4;
    v8s frag;
    #pragma unroll
    for (int j = 0; j < 8; ++j) {
      int d = b0 + lm - 8 * quad - j;
      float v = 0.0f;
      if (d >= 0 && d < T_DIM) v = __expf(W[d * H_DIM + h]);
      else if (d == T_DIM) v = 1.0f;
      frag[j] = (short)f2bf(v);
    }
    *(v8s*)(fragA + (size_t)tid * 8) = frag;
    return;
  }
  bid -= J1_BLOCKS;
  {
    int b = bid / NST, st = bid - b * NST;
    int s0 = st * 64;
    int tid = threadIdx.x;
    int c = tid & 63, r4 = tid >> 6;
    #pragma unroll
    for (int i = 0; i < 16; ++i) {
      int sl = r4 * 16 + i;
      int s = s0 + sl;
      tile[sl][c] = (s < T_DIM) ? x[((size_t)b * T_DIM + s) * 64 + c] : 0.0f;
    }
    __syncthreads();
    // chunk byte layout: dd*128 + p*16 + j*2 holds s_local = (p^(dd&7))*8 + j
    int dd = tid >> 2, pb = (tid & 3) * 2;
    unsigned short* dst = xT + ((size_t)(b * NST + st) << 12) + dd * 64;
    #pragma unroll
    for (int e = 0; e < 2; ++e) {
      int p = pb + e;
      int sb = ((p ^ (dd & 7)) << 3);
      v8s o;
      #pragma unroll
      for (int j = 0; j < 8; ++j) o[j] = (short)f2bf(tile[sb + j][dd]);
      *(v8s*)(dst + p * 8) = o;
    }
  }
}

// Fat blocks (bid < MM_BLOCKS): block = (h, b-pair, 128 rows), 4 waves:
//   wm = w&1 owns a 64-row half (tw = t0 + 64*wm), wb = w>>1 owns one b.
// K loop in BK=64 steps. Schedule: 3-buffer rotation, ONE barrier per step:
//   wait vmcnt(mine for step it) -> s_barrier (everyone's stage(it) landed AND
//   everyone finished compute(it-1), so buf[(it+2)%3] is write-safe) ->
//   issue STAGE(it+2) overlapped with the MFMA cluster -> loop.
// Counted vmcnt (2 stages in flight), never drained in the main loop.
// A-frag dedup: kk=0 uses entries {2..5}+4wm, kk=1 uses {0..3}+4wm -> load 6.
// h = bid&7 pins one head per XCD (L2 working set fragA[h]+xT ~2.3MB/XCD).
// Trailing blocks: head-H l2norm of xp (independent of prep; overlaps MM).
__global__ __launch_bounds__(256) void toeplitz_mm(const float* __restrict__ x,
                                                   const unsigned short* __restrict__ fragA,
                                                   const unsigned short* __restrict__ xT,
                                                   float* __restrict__ out) {
  __shared__ __align__(16) char smem[3][BUFSZ];

  int bid = blockIdx.x;
  if (bid >= MM_BLOCKS) {  // head H: single l2norm of xp
    int row = (bid - MM_BLOCKS) * 4 + (threadIdx.x >> 6);
    int b = row / TP1, t = row - b * TP1;
    int dd = threadIdx.x & 63;
    float v = (t < T_DIM) ? x[((size_t)b * T_DIM + t) * 64 + dd] : 0.0f;
    float ss = v * v;
    ss += __shfl_xor(ss, 1);  ss += __shfl_xor(ss, 2);
    ss += __shfl_xor(ss, 4);  ss += __shfl_xor(ss, 8);
    ss += __shfl_xor(ss, 16); ss += __shfl_xor(ss, 32);
    float inv = 1.0f / (sqrtf(ss) + EPS);
    __builtin_nontemporal_store(v * inv,
        &out[(((size_t)(H_DIM * B_DIM + b) * TP1 + t) << 6) + dd]);
    return;
  }

  const int lane = threadIdx.x & 63;
  const int w    = threadIdx.x >> 6;
  const int wm   = w & 1;
  const int wb   = w >> 1;
  const int lm   = lane & 15;
  const int quad = lane >> 4;

  const int h   = bid & 7;
  const int bg  = (bid >> 3) & 3;
  const int lvl = bid >> 5;                 // 0..16, longest tiles first
  const int t0  = T_DIM - lvl * 128;
  const int tw  = t0 + 64 * wm;
  const int b   = bg * 2 + wb;
  const bool active = (tw <= T_DIM);
  const int cap = tw + 32;                  // last valid 32-chunk base for this wave

  const int NS = (min(t0 + 96, T_DIM) >> 6) + 1;   // always >= 2

  const unsigned short* fA = fragA + (size_t)h * NFRAG * 512 + lane * 8;

  // Stage step 'it' into smem[bufi]: units 0..9 = A entries E0p..E0p+9 (1KB each),
  // units 10..25 = B pieces (2 b's x 8 x 1KB). Unit u = w + 4*i: waves 0,1 issue
  // 7 loads; waves 2,3 issue 6 (used for the counted vmcnt below).
#define STAGE(bufi, it) do {                                                   \
    int _s0 = (it) << 6;                                                       \
    int _E0p = ((t0 - _s0 + 32) >> 4) + 6;                                     \
    const unsigned short* _A = fA + (size_t)_E0p * 512;                        \
    const unsigned short* _B = xT + ((size_t)((bg * 2) * NST + (_s0 >> 6)) << 12) + lane * 8; \
    char* _lb = &smem[bufi][0];                                                \
    _Pragma("unroll")                                                          \
    for (int _i = 0; _i < 7; ++_i) {                                           \
      int _u = w + _i * 4;                                                     \
      if (_u < 26) {                                                           \
        const unsigned short* _src = (_u < 10)                                 \
            ? (_A + (size_t)_u * 512)                                          \
            : (_B + (((_u - 10) >> 3) * (NST * 4096)) + (((_u - 10) & 7) * 512)); \
        load_lds16(_src, _lb + _u * 1024);                                     \
      }                                                                        \
    }                                                                          \
  } while (0)

  v4f acc[4][4] = {};  // rows tw+16*mt+4*quad+r, cols (b, 16*nt+lm)

  STAGE(0, 0);
  STAGE(1, 1);
  int it3 = 0;                               // it % 3
  for (int it = 0; it < NS; ++it) {
    // Wait for step-it's stage (the older of the <=2 in flight), never drain early.
    if (it < NS - 1) {
      if (w < 2) asm volatile("s_waitcnt vmcnt(7)" ::: "memory");
      else       asm volatile("s_waitcnt vmcnt(6)" ::: "memory");
    } else {
      asm volatile("s_waitcnt vmcnt(0)" ::: "memory");
    }
    __builtin_amdgcn_s_barrier();            // all stage(it) landed; compute(it-1) done
    __builtin_amdgcn_sched_barrier(0);       // no ds_read/stage hoists above this point

    if (it + 2 < NS) {                       // overlapped with compute below
      int tgt = it3 + 2; if (tgt >= 3) tgt -= 3;
      STAGE(tgt, it + 2);
    }

    const char* Ab = &smem[it3][0];
    const char* Bb = Ab + AREG + wb * 8192;
    int s0 = it << 6;
    __builtin_amdgcn_s_setprio(1);
    v8s af6[6];
    #pragma unroll
    for (int e = 0; e < 6; ++e)
      af6[e] = *(const v8s*)(Ab + (e + 4 * wm) * 1024 + lane * 16);
    #pragma unroll
    for (int kk = 0; kk < 2; ++kk) {
      if (active && (s0 + 32 * kk <= cap)) {
        v8s bf[4];
        #pragma unroll
        for (int nt = 0; nt < 4; ++nt)
          bf[nt] = *(const v8s*)(Bb + nt * 2048 + lm * 128 +
                                 ((((kk << 2) | quad) ^ (lm & 7)) << 4));
        #pragma unroll
        for (int mt = 0; mt < 4; ++mt)
          #pragma unroll
          for (int nt = 0; nt < 4; ++nt)
            acc[mt][nt] = __builtin_amdgcn_mfma_f32_16x16x32_bf16(
                af6[(kk ? 0 : 2) + mt], bf[nt], acc[mt][nt], 0, 0, 0);
      }
    }
    __builtin_amdgcn_s_setprio(0);
    if (++it3 == 3) it3 = 0;
  }

  if (!active) return;

  // Epilogue: double l2-norm over dd (softmax Z cancels up to eps ~3e-7).
  // C/D layout: col = lane&15 (dd offset), row = quad*4 + reg.
  #pragma unroll
  for (int mt = 0; mt < 4; ++mt) {
    #pragma unroll
    for (int r = 0; r < 4; ++r) {
      float ss = 0.0f;
      #pragma unroll
      for (int nt = 0; nt < 4; ++nt) { float a = acc[mt][nt][r]; ss += a * a; }
      ss += __shfl_xor(ss, 1);
      ss += __shfl_xor(ss, 2);
      ss += __shfl_xor(ss, 4);
      ss += __shfl_xor(ss, 8);
      int t = tw + 16 * mt + 4 * quad + r;
      if (t <= T_DIM) {
        float n1 = sqrtf(ss);
        float u  = n1 / (n1 + EPS);
        float inv = 1.0f / ((n1 + EPS) * (u + EPS));
        float* op = out + (((size_t)(h * B_DIM + b) * TP1 + t) << 6) + lm;
        #pragma unroll
        for (int nt = 0; nt < 4; ++nt)
          __builtin_nontemporal_store(acc[mt][nt][r] * inv, op + 16 * nt);
      }
    }
  }
#undef STAGE
}

extern "C" void kernel_launch(void* const* d_in, const int* in_sizes, int n_in,
                              void* d_out, int out_size, void* d_ws, size_t ws_size,
                              hipStream_t stream) {
  const float* x = (const float*)d_in[0];   // [8, 2048, 64] fp32
  const float* W = (const float*)d_in[1];   // [2048, 8] fp32
  float* out = (float*)d_out;               // [9, 8, 2049, 64] fp32

  unsigned short* xT    = (unsigned short*)d_ws;                    // 8*33*8192 = 2,162,688 B
  unsigned short* fragA = (unsigned short*)((char*)d_ws + 2162688); // 8*146*1024 = 1,196,032 B

  hipLaunchKernelGGL(prep, dim3(J1_BLOCKS + J2_BLOCKS), dim3(256), 0, stream,
                     x, W, fragA, xT);
  hipLaunchKernelGGL(toeplitz_mm, dim3(MM_BLOCKS + J3_BLOCKS), dim3(256), 0, stream,
                     x, fragA, xT, out);
}

// Round 4
// 101.469 us; speedup vs baseline: 1.0403x; 1.0088x over previous
//
#include <hip/hip_runtime.h>

#define EPS 1e-7f
#define T_DIM 2048
#define TP1   2049
#define H_DIM 8
#define B_DIM 8

#define NFRAG 146          // fb_phys in [0,146): b0 = fbp*16 - 160 (first 8 entries all-zero pad)
#define NST   33           // 64-wide s-tiles per b (covers s in [0,2112), zero past 2048)
#define AREG  10240        // A region bytes per LDS buffer (10 x 1KB entries)
#define BUFSZ 26624        // A 10KB + B 2 x 8KB

#define J1_BLOCKS 292      // 8*146*64/256 fragA entries
#define J2_BLOCKS 264      // 8 b * 33 st transpose tiles
#define J3_BLOCKS 4098     // head-H rows: 8*2049/4
#define MM_BLOCKS 544      // 17 t0-levels * 4 b-groups * 8 heads

typedef short v8s __attribute__((ext_vector_type(8)));
typedef float v4f __attribute__((ext_vector_type(4)));

static __device__ __forceinline__ unsigned short f2bf(float f) {
  union { float f; unsigned u; } v; v.f = f;
  unsigned r = v.u + 0x7fffu + ((v.u >> 16) & 1u);  // RTNE
  return (unsigned short)(r >> 16);
}

static __device__ __forceinline__ void load_lds16(const void* g, void* l) {
  __builtin_amdgcn_global_load_lds(
      (const __attribute__((address_space(1))) unsigned int*)g,
      (__attribute__((address_space(3))) unsigned int*)l, 16, 0, 0);
}

// prep: [J1] MFMA A-fragment table, [J2] x -> bf16 transpose into swizzled 8KB
// chunks xT[b][st][dd][slot^(dd&7)][8], [J3] head-H l2norm output.
// All three are independent of each other; LDS here is only 16.6KB so J3's
// 4098 tiny blocks run at high blocks/CU (unlike when they lived in the 53KB-LDS
// MM kernel and were capped at 2-3/CU).
__global__ __launch_bounds__(256) void prep(const float* __restrict__ x,
                                            const float* __restrict__ W,
                                            unsigned short* __restrict__ fragA,
                                            unsigned short* __restrict__ xT,
                                            float* __restrict__ out) {
  __shared__ float tile[64][65];
  int bid = blockIdx.x;
  if (bid < J1_BLOCKS) {
    // fragA[((h*NFRAG+fbp)*64+lane)*8]: A[m=lm][k=8q+j] = k_h[b0+lm-8q-j], b0=fbp*16-160
    int tid = bid * 256 + threadIdx.x;
    int blk = tid >> 6, lane = tid & 63;
    int h = blk / NFRAG, fbp = blk - h * NFRAG;
    int b0 = fbp * 16 - 160;
    int lm = lane & 15, quad = lane >> 4;
    v8s frag;
    #pragma unroll
    for (int j = 0; j < 8; ++j) {
      int d = b0 + lm - 8 * quad - j;
      float v = 0.0f;
      if (d >= 0 && d < T_DIM) v = __expf(W[d * H_DIM + h]);
      else if (d == T_DIM) v = 1.0f;
      frag[j] = (short)f2bf(v);
    }
    *(v8s*)(fragA + (size_t)tid * 8) = frag;
    return;
  }
  bid -= J1_BLOCKS;
  if (bid < J2_BLOCKS) {
    int b = bid / NST, st = bid - b * NST;
    int s0 = st * 64;
    int tid = threadIdx.x;
    int c = tid & 63, r4 = tid >> 6;
    #pragma unroll
    for (int i = 0; i < 16; ++i) {
      int sl = r4 * 16 + i;
      int s = s0 + sl;
      tile[sl][c] = (s < T_DIM) ? x[((size_t)b * T_DIM + s) * 64 + c] : 0.0f;
    }
    __syncthreads();
    // chunk byte layout: dd*128 + p*16 + j*2 holds s_local = (p^(dd&7))*8 + j
    int dd = tid >> 2, pb = (tid & 3) * 2;
    unsigned short* dst = xT + ((size_t)(b * NST + st) << 12) + dd * 64;
    #pragma unroll
    for (int e = 0; e < 2; ++e) {
      int p = pb + e;
      int sb = ((p ^ (dd & 7)) << 3);
      v8s o;
      #pragma unroll
      for (int j = 0; j < 8; ++j) o[j] = (short)f2bf(tile[sb + j][dd]);
      *(v8s*)(dst + p * 8) = o;
    }
    return;
  }
  bid -= J2_BLOCKS;
  {  // head H: single l2norm of xp
    int row = bid * 4 + (threadIdx.x >> 6);
    if (row >= B_DIM * TP1) return;
    int b = row / TP1, t = row - b * TP1;
    int dd = threadIdx.x & 63;
    float v = (t < T_DIM) ? x[((size_t)b * T_DIM + t) * 64 + dd] : 0.0f;
    float ss = v * v;
    ss += __shfl_xor(ss, 1);  ss += __shfl_xor(ss, 2);
    ss += __shfl_xor(ss, 4);  ss += __shfl_xor(ss, 8);
    ss += __shfl_xor(ss, 16); ss += __shfl_xor(ss, 32);
    float inv = 1.0f / (sqrtf(ss) + EPS);
    __builtin_nontemporal_store(v * inv,
        &out[(((size_t)(H_DIM * B_DIM + b) * TP1 + t) << 6) + dd]);
  }
}

// block = (h, b-pair, 128 rows), 4 waves: wm = w&1 owns a 64-row half
// (tw = t0 + 64*wm), wb = w>>1 owns one b. K loop in BK=64 steps.
// 2 LDS buffers (53.2KB) -> 3 blocks/CU = 12 waves/CU: co-resident blocks
// hide each other's barrier/vmcnt stalls (m114 TLP), which schedule surgery
// at 2 blocks/CU could not. Counted-vmcnt double buffer: 2 stages in flight,
// wait vmcnt(mine) (never drain mid-loop), 2 barriers/step, stage(it+2)
// issued right after the read-completion barrier so its loads fly for a
// whole step. A-frag dedup: kk=0 uses entries {2..5}+4wm, kk=1 {0..3}+4wm
// -> load 6 once. h = bid&7 pins one head per XCD (L2 set ~2.3MB/XCD).
__global__ __launch_bounds__(256) void toeplitz_mm(const unsigned short* __restrict__ fragA,
                                                   const unsigned short* __restrict__ xT,
                                                   float* __restrict__ out) {
  __shared__ __align__(16) char smem[2][BUFSZ];

  const int lane = threadIdx.x & 63;
  const int w    = threadIdx.x >> 6;
  const int wm   = w & 1;
  const int wb   = w >> 1;
  const int lm   = lane & 15;
  const int quad = lane >> 4;

  const int bid = blockIdx.x;
  const int h   = bid & 7;
  const int bg  = (bid >> 3) & 3;
  const int lvl = bid >> 5;                 // 0..16, longest tiles first
  const int t0  = T_DIM - lvl * 128;
  const int tw  = t0 + 64 * wm;
  const int b   = bg * 2 + wb;
  const bool active = (tw <= T_DIM);
  const int cap = tw + 32;                  // last valid 32-chunk base for this wave

  const int NS = (min(t0 + 96, T_DIM) >> 6) + 1;   // always >= 2

  const unsigned short* fA = fragA + (size_t)h * NFRAG * 512 + lane * 8;

  // Stage step 'it' into smem[bufi]: units 0..9 = A entries E0p..E0p+9 (1KB each),
  // units 10..25 = B pieces (2 b's x 8 x 1KB). Unit u = w + 4*i: waves 0,1 issue
  // 7 loads; waves 2,3 issue 6 (used for the counted vmcnt below).
#define STAGE(bufi, it) do {                                                   \
    int _s0 = (it) << 6;                                                       \
    int _E0p = ((t0 - _s0 + 32) >> 4) + 6;                                     \
    const unsigned short* _A = fA + (size_t)_E0p * 512;                        \
    const unsigned short* _B = xT + ((size_t)((bg * 2) * NST + (_s0 >> 6)) << 12) + lane * 8; \
    char* _lb = &smem[bufi][0];                                                \
    _Pragma("unroll")                                                          \
    for (int _i = 0; _i < 7; ++_i) {                                           \
      int _u = w + _i * 4;                                                     \
      if (_u < 26) {                                                           \
        const unsigned short* _src = (_u < 10)                                 \
            ? (_A + (size_t)_u * 512)                                          \
            : (_B + (((_u - 10) >> 3) * (NST * 4096)) + (((_u - 10) & 7) * 512)); \
        load_lds16(_src, _lb + _u * 1024);                                     \
      }                                                                        \
    }                                                                          \
  } while (0)

  v4f acc[4][4] = {};  // rows tw+16*mt+4*quad+r, cols (b, 16*nt+lm)

  STAGE(0, 0);
  STAGE(1, 1);
  int buf = 0;
  for (int it = 0; it < NS; ++it) {
    // Wait for step-it's stage (the older of the <=2 in flight), never drain early.
    if (it < NS - 1) {
      if (w < 2) asm volatile("s_waitcnt vmcnt(7)" ::: "memory");
      else       asm volatile("s_waitcnt vmcnt(6)" ::: "memory");
    } else {
      asm volatile("s_waitcnt vmcnt(0)" ::: "memory");
    }
    __builtin_amdgcn_s_barrier();            // everyone's stage(it) landed
    __builtin_amdgcn_sched_barrier(0);       // no ds_read hoists above this point

    const char* Ab = &smem[buf][0];
    const char* Bb = Ab + AREG + wb * 8192;
    int s0 = it << 6;
    __builtin_amdgcn_s_setprio(1);
    v8s af6[6];
    #pragma unroll
    for (int e = 0; e < 6; ++e)
      af6[e] = *(const v8s*)(Ab + (e + 4 * wm) * 1024 + lane * 16);
    #pragma unroll
    for (int kk = 0; kk < 2; ++kk) {
      if (active && (s0 + 32 * kk <= cap)) {
        v8s bf[4];
        #pragma unroll
        for (int nt = 0; nt < 4; ++nt)
          bf[nt] = *(const v8s*)(Bb + nt * 2048 + lm * 128 +
                                 ((((kk << 2) | quad) ^ (lm & 7)) << 4));
        #pragma unroll
        for (int mt = 0; mt < 4; ++mt)
          #pragma unroll
          for (int nt = 0; nt < 4; ++nt)
            acc[mt][nt] = __builtin_amdgcn_mfma_f32_16x16x32_bf16(
                af6[(kk ? 0 : 2) + mt], bf[nt], acc[mt][nt], 0, 0, 0);
      }
    }
    __builtin_amdgcn_s_setprio(0);
    __builtin_amdgcn_sched_barrier(0);
    __builtin_amdgcn_s_barrier();            // all waves done reading smem[buf]
    if (it + 2 < NS) STAGE(buf, it + 2);     // loads fly for a whole step
    buf ^= 1;
  }

  if (!active) return;

  // Epilogue: double l2-norm over dd (softmax Z cancels up to eps ~3e-7).
  // C/D layout: col = lane&15 (dd offset), row = quad*4 + reg.
  #pragma unroll
  for (int mt = 0; mt < 4; ++mt) {
    #pragma unroll
    for (int r = 0; r < 4; ++r) {
      float ss = 0.0f;
      #pragma unroll
      for (int nt = 0; nt < 4; ++nt) { float a = acc[mt][nt][r]; ss += a * a; }
      ss += __shfl_xor(ss, 1);
      ss += __shfl_xor(ss, 2);
      ss += __shfl_xor(ss, 4);
      ss += __shfl_xor(ss, 8);
      int t = tw + 16 * mt + 4 * quad + r;
      if (t <= T_DIM) {
        float n1 = sqrtf(ss);
        float u  = n1 / (n1 + EPS);
        float inv = 1.0f / ((n1 + EPS) * (u + EPS));
        float* op = out + (((size_t)(h * B_DIM + b) * TP1 + t) << 6) + lm;
        #pragma unroll
        for (int nt = 0; nt < 4; ++nt)
          __builtin_nontemporal_store(acc[mt][nt][r] * inv, op + 16 * nt);
      }
    }
  }
#undef STAGE
}

extern "C" void kernel_launch(void* const* d_in, const int* in_sizes, int n_in,
                              void* d_out, int out_size, void* d_ws, size_t ws_size,
                              hipStream_t stream) {
  const float* x = (const float*)d_in[0];   // [8, 2048, 64] fp32
  const float* W = (const float*)d_in[1];   // [2048, 8] fp32
  float* out = (float*)d_out;               // [9, 8, 2049, 64] fp32

  unsigned short* xT    = (unsigned short*)d_ws;                    // 8*33*8192 = 2,162,688 B
  unsigned short* fragA = (unsigned short*)((char*)d_ws + 2162688); // 8*146*1024 = 1,196,032 B

  hipLaunchKernelGGL(prep, dim3(J1_BLOCKS + J2_BLOCKS + J3_BLOCKS), dim3(256), 0, stream,
                     x, W, fragA, xT, out);
  hipLaunchKernelGGL(toeplitz_mm, dim3(MM_BLOCKS), dim3(256), 0, stream,
                     fragA, xT, out);
}

// Round 5
// 101.118 us; speedup vs baseline: 1.0439x; 1.0035x over previous
//
#include <hip/hip_runtime.h>

#define EPS 1e-7f
#define T_DIM 2048
#define TP1   2049
#define H_DIM 8
#define B_DIM 8

#define NFRAG 146          // fb_phys in [0,146): b0 = fbp*16 - 160 (first 8 entries all-zero pad)
#define NST   33           // 64-wide s-tiles per b (covers s in [0,2112), zero past 2048)
#define AREG  10240        // A region bytes per LDS buffer (10 x 1KB entries)
#define BUFSZ 26624        // A 10KB + B 2 x 8KB

#define J1_BLOCKS 292      // 8*146*64/256 fragA entries
#define J2_BLOCKS 264      // 8 b * 33 st transpose tiles
#define J3_BLOCKS 4098     // head-H rows: 8*2049/4
#define MM_BLOCKS 544      // 17 t0-levels * 4 b-groups * 8 heads

typedef short v8s __attribute__((ext_vector_type(8)));
typedef float v4f __attribute__((ext_vector_type(4)));

static __device__ __forceinline__ unsigned short f2bf(float f) {
  union { float f; unsigned u; } v; v.f = f;
  unsigned r = v.u + 0x7fffu + ((v.u >> 16) & 1u);  // RTNE
  return (unsigned short)(r >> 16);
}

static __device__ __forceinline__ void load_lds16(const void* g, void* l) {
  __builtin_amdgcn_global_load_lds(
      (const __attribute__((address_space(1))) unsigned int*)g,
      (__attribute__((address_space(3))) unsigned int*)l, 16, 0, 0);
}

// prep: [J1] MFMA A-fragment table, [J2] x -> bf16 transpose into swizzled 8KB
// chunks xT[b][st][dd][slot^(dd&7)][8], [J3] head-H l2norm output.
__global__ __launch_bounds__(256) void prep(const float* __restrict__ x,
                                            const float* __restrict__ W,
                                            unsigned short* __restrict__ fragA,
                                            unsigned short* __restrict__ xT,
                                            float* __restrict__ out) {
  __shared__ float tile[64][65];
  int bid = blockIdx.x;
  if (bid < J1_BLOCKS) {
    // fragA[((h*NFRAG+fbp)*64+lane)*8]: A[m=lm][k=8q+j] = k_h[b0+lm-8q-j], b0=fbp*16-160
    int tid = bid * 256 + threadIdx.x;
    int blk = tid >> 6, lane = tid & 63;
    int h = blk / NFRAG, fbp = blk - h * NFRAG;
    int b0 = fbp * 16 - 160;
    int lm = lane & 15, quad = lane >> 4;
    v8s frag;
    #pragma unroll
    for (int j = 0; j < 8; ++j) {
      int d = b0 + lm - 8 * quad - j;
      float v = 0.0f;
      if (d >= 0 && d < T_DIM) v = __expf(W[d * H_DIM + h]);
      else if (d == T_DIM) v = 1.0f;
      frag[j] = (short)f2bf(v);
    }
    *(v8s*)(fragA + (size_t)tid * 8) = frag;
    return;
  }
  bid -= J1_BLOCKS;
  if (bid < J2_BLOCKS) {
    int b = bid / NST, st = bid - b * NST;
    int s0 = st * 64;
    int tid = threadIdx.x;
    int c = tid & 63, r4 = tid >> 6;
    #pragma unroll
    for (int i = 0; i < 16; ++i) {
      int sl = r4 * 16 + i;
      int s = s0 + sl;
      tile[sl][c] = (s < T_DIM) ? x[((size_t)b * T_DIM + s) * 64 + c] : 0.0f;
    }
    __syncthreads();
    // chunk byte layout: dd*128 + p*16 + j*2 holds s_local = (p^(dd&7))*8 + j
    int dd = tid >> 2, pb = (tid & 3) * 2;
    unsigned short* dst = xT + ((size_t)(b * NST + st) << 12) + dd * 64;
    #pragma unroll
    for (int e = 0; e < 2; ++e) {
      int p = pb + e;
      int sb = ((p ^ (dd & 7)) << 3);
      v8s o;
      #pragma unroll
      for (int j = 0; j < 8; ++j) o[j] = (short)f2bf(tile[sb + j][dd]);
      *(v8s*)(dst + p * 8) = o;
    }
    return;
  }
  bid -= J2_BLOCKS;
  {  // head H: single l2norm of xp
    int row = bid * 4 + (threadIdx.x >> 6);
    if (row >= B_DIM * TP1) return;
    int b = row / TP1, t = row - b * TP1;
    int dd = threadIdx.x & 63;
    float v = (t < T_DIM) ? x[((size_t)b * T_DIM + t) * 64 + dd] : 0.0f;
    float ss = v * v;
    ss += __shfl_xor(ss, 1);  ss += __shfl_xor(ss, 2);
    ss += __shfl_xor(ss, 4);  ss += __shfl_xor(ss, 8);
    ss += __shfl_xor(ss, 16); ss += __shfl_xor(ss, 32);
    float inv = 1.0f / (sqrtf(ss) + EPS);
    __builtin_nontemporal_store(v * inv,
        &out[(((size_t)(H_DIM * B_DIM + b) * TP1 + t) << 6) + dd]);
  }
}

// block = (h, b-pair, 128 rows), 4 waves: wm = w&1 owns a 64-row half
// (tw = t0 + 64*wm), wb = w>>1 owns one b. K loop in BK=64 steps.
// CU load balance: dispatch pairs blocks (x+8c, x+8c+256) on one CU ->
// lvl pair (k, k+8). Old longest-first gave per-CU step sums 51..24 (2.1x
// imbalance). New bijection lvl = k<8 ? k : (k<16 ? 23-k : 16) pairs
// (k, 15-k) -> 37-38 steps on EVERY CU (lvl16 2-step blocks trail).
// Pipeline: 3 LDS buffers (79.9KB, still 2 blocks/CU since grid-limited),
// 3 stages in flight, counted waits vmcnt(14/12 -> 7/6 -> 0): each stage
// gets TWO full steps of latency budget. Restage into buffer (it%3) right
// after the read-completion barrier. A-frag dedup: kk=0 uses entries
// {2..5}+4wm, kk=1 {0..3}+4wm -> load 6 once. h = bid&7 pins one head
// per XCD (L2 set ~2.3MB/XCD).
__global__ __launch_bounds__(256) void toeplitz_mm(const unsigned short* __restrict__ fragA,
                                                   const unsigned short* __restrict__ xT,
                                                   float* __restrict__ out) {
  __shared__ __align__(16) char smem[3][BUFSZ];

  const int lane = threadIdx.x & 63;
  const int w    = threadIdx.x >> 6;
  const int wm   = w & 1;
  const int wb   = w >> 1;
  const int lm   = lane & 15;
  const int quad = lane >> 4;

  const int bid = blockIdx.x;
  const int h   = bid & 7;
  const int bg  = (bid >> 3) & 3;
  const int k   = bid >> 5;                 // 0..16
  const int lvl = (k < 8) ? k : ((k < 16) ? 23 - k : 16);  // CU-balanced pairing
  const int t0  = T_DIM - lvl * 128;
  const int tw  = t0 + 64 * wm;
  const int b   = bg * 2 + wb;
  const bool active = (tw <= T_DIM);
  const int cap = tw + 32;                  // last valid 32-chunk base for this wave

  const int NS = (min(t0 + 96, T_DIM) >> 6) + 1;   // always >= 2

  const unsigned short* fA = fragA + (size_t)h * NFRAG * 512 + lane * 8;

  // Stage step 'it' into smem[bufi]: units 0..9 = A entries E0p..E0p+9 (1KB each),
  // units 10..25 = B pieces (2 b's x 8 x 1KB). Unit u = w + 4*i: waves 0,1 issue
  // 7 loads; waves 2,3 issue 6 (used for the counted vmcnt below).
#define STAGE(bufi, it) do {                                                   \
    int _s0 = (it) << 6;                                                       \
    int _E0p = ((t0 - _s0 + 32) >> 4) + 6;                                     \
    const unsigned short* _A = fA + (size_t)_E0p * 512;                        \
    const unsigned short* _B = xT + ((size_t)((bg * 2) * NST + (_s0 >> 6)) << 12) + lane * 8; \
    char* _lb = &smem[bufi][0];                                                \
    _Pragma("unroll")                                                          \
    for (int _i = 0; _i < 7; ++_i) {                                           \
      int _u = w + _i * 4;                                                     \
      if (_u < 26) {                                                           \
        const unsigned short* _src = (_u < 10)                                 \
            ? (_A + (size_t)_u * 512)                                          \
            : (_B + (((_u - 10) >> 3) * (NST * 4096)) + (((_u - 10) & 7) * 512)); \
        load_lds16(_src, _lb + _u * 1024);                                     \
      }                                                                        \
    }                                                                          \
  } while (0)

  v4f acc[4][4] = {};  // rows tw+16*mt+4*quad+r, cols (b, 16*nt+lm)

  STAGE(0, 0);
  STAGE(1, 1);
  if (NS > 2) STAGE(2, 2);
  int it3 = 0;                               // it % 3
  for (int it = 0; it < NS; ++it) {
    // Wait until stage(it) has landed: allow (stages still in flight) to remain.
    int rem = NS - 1 - it; if (rem > 2) rem = 2;
    if (w < 2) {
      if (rem == 2)      asm volatile("s_waitcnt vmcnt(14)" ::: "memory");
      else if (rem == 1) asm volatile("s_waitcnt vmcnt(7)"  ::: "memory");
      else               asm volatile("s_waitcnt vmcnt(0)"  ::: "memory");
    } else {
      if (rem == 2)      asm volatile("s_waitcnt vmcnt(12)" ::: "memory");
      else if (rem == 1) asm volatile("s_waitcnt vmcnt(6)"  ::: "memory");
      else               asm volatile("s_waitcnt vmcnt(0)"  ::: "memory");
    }
    __builtin_amdgcn_s_barrier();            // everyone's stage(it) landed
    __builtin_amdgcn_sched_barrier(0);       // no ds_read hoists above this point

    const char* Ab = &smem[it3][0];
    const char* Bb = Ab + AREG + wb * 8192;
    int s0 = it << 6;
    __builtin_amdgcn_s_setprio(1);
    v8s af6[6];
    #pragma unroll
    for (int e = 0; e < 6; ++e)
      af6[e] = *(const v8s*)(Ab + (e + 4 * wm) * 1024 + lane * 16);
    #pragma unroll
    for (int kk = 0; kk < 2; ++kk) {
      if (active && (s0 + 32 * kk <= cap)) {
        v8s bf[4];
        #pragma unroll
        for (int nt = 0; nt < 4; ++nt)
          bf[nt] = *(const v8s*)(Bb + nt * 2048 + lm * 128 +
                                 ((((kk << 2) | quad) ^ (lm & 7)) << 4));
        #pragma unroll
        for (int mt = 0; mt < 4; ++mt)
          #pragma unroll
          for (int nt = 0; nt < 4; ++nt)
            acc[mt][nt] = __builtin_amdgcn_mfma_f32_16x16x32_bf16(
                af6[(kk ? 0 : 2) + mt], bf[nt], acc[mt][nt], 0, 0, 0);
      }
    }
    __builtin_amdgcn_s_setprio(0);
    __builtin_amdgcn_sched_barrier(0);
    __builtin_amdgcn_s_barrier();            // all waves done reading smem[it3]
    if (it + 3 < NS) STAGE(it3, it + 3);     // loads fly for TWO whole steps
    if (++it3 == 3) it3 = 0;
  }

  if (!active) return;

  // Epilogue: double l2-norm over dd (softmax Z cancels up to eps ~3e-7).
  // C/D layout: col = lane&15 (dd offset), row = quad*4 + reg.
  #pragma unroll
  for (int mt = 0; mt < 4; ++mt) {
    #pragma unroll
    for (int r = 0; r < 4; ++r) {
      float ss = 0.0f;
      #pragma unroll
      for (int nt = 0; nt < 4; ++nt) { float a = acc[mt][nt][r]; ss += a * a; }
      ss += __shfl_xor(ss, 1);
      ss += __shfl_xor(ss, 2);
      ss += __shfl_xor(ss, 4);
      ss += __shfl_xor(ss, 8);
      int t = tw + 16 * mt + 4 * quad + r;
      if (t <= T_DIM) {
        float n1 = sqrtf(ss);
        float u  = n1 / (n1 + EPS);
        float inv = 1.0f / ((n1 + EPS) * (u + EPS));
        float* op = out + (((size_t)(h * B_DIM + b) * TP1 + t) << 6) + lm;
        #pragma unroll
        for (int nt = 0; nt < 4; ++nt)
          __builtin_nontemporal_store(acc[mt][nt][r] * inv, op + 16 * nt);
      }
    }
  }
#undef STAGE
}

extern "C" void kernel_launch(void* const* d_in, const int* in_sizes, int n_in,
                              void* d_out, int out_size, void* d_ws, size_t ws_size,
                              hipStream_t stream) {
  const float* x = (const float*)d_in[0];   // [8, 2048, 64] fp32
  const float* W = (const float*)d_in[1];   // [2048, 8] fp32
  float* out = (float*)d_out;               // [9, 8, 2049, 64] fp32

  unsigned short* xT    = (unsigned short*)d_ws;                    // 8*33*8192 = 2,162,688 B
  unsigned short* fragA = (unsigned short*)((char*)d_ws + 2162688); // 8*146*1024 = 1,196,032 B

  hipLaunchKernelGGL(prep, dim3(J1_BLOCKS + J2_BLOCKS + J3_BLOCKS), dim3(256), 0, stream,
                     x, W, fragA, xT, out);
  hipLaunchKernelGGL(toeplitz_mm, dim3(MM_BLOCKS), dim3(256), 0, stream,
                     fragA, xT, out);
}